// Round 7
// baseline (292.456 us; speedup 1.0000x reference)
//
#include <hip/hip_runtime.h>

// RBFolution: out[b,y,x,f] = exp(-beta[f] * (||patch||^2 - 2 patch.ccs[:,f] + ||ccs[:,f]||^2))
// x: [32,112,112,32] f32, ccs: [288,128] f32, beta: [128] f32, out: [32,110,110,128] f32
//
// bf16 MFMA implicit GEMM; p_sq/c_sq fp32-exact (only cross term bf16, err ~1e-5).
// R11: PIPELINED 8-row blocks. Ledger: write-amp fixed (R9, full-line nt stores, -14us);
// TLP refuted (R5/R8); A-hoist refuted (R10). Remaining gap: main ~113us vs ~44us
// device floor with ALL pipes idle -> intra-block stage/compute serialization.
// New structure: block owns 8 output rows = 4 strips x 2 rows; 6-slot LDS row ring
// (slot = row_offset % 6). Per strip: issue next-2-rows global loads into regs BEFORE
// MFMA (T14 async-stage: HBM hides under compute) -> barrier -> cvt+LDS-write+colsum
// -> barrier -> p_sq -> barrier. Only the 4-row prologue stage is exposed.
// Refetch 10/8 = 1.25x (fetch 64MB). Grid 14x32=448: ~single block-generation.

typedef __attribute__((ext_vector_type(8))) short bf16x8;
typedef __attribute__((ext_vector_type(4))) float f32x4;

#define HH 112
#define WW 112
#define CC 32
#define HO 110
#define WO 110
#define NF 128
#define KD 288
#define RPX 114        // pixels per staged row slot (reads reach px 113)
#define XP 32          // bf16 elems per pixel (64 B)
#define SLOTS 6        // LDS row ring depth
#define CSP 116        // colsum row pitch (reads reach col 113)

__device__ __forceinline__ unsigned short f32_to_bf16(float f) {
    unsigned u = __float_as_uint(f);
    unsigned r = u + 0x7FFFu + ((u >> 16) & 1u);   // round-to-nearest-even
    return (unsigned short)(r >> 16);
}

// --- Prologue: ccs [288][128] f32 -> ccs_t [128][288] bf16 (all blocks);
//     block 0 threads 0..127 also compute c_sq[f] = sum_d ccs[d][f]^2.
__global__ __launch_bounds__(256) void rbf_prologue(const float* __restrict__ ccs,
                                                    unsigned short* __restrict__ ccs_t,
                                                    float* __restrict__ c_sq) {
    int idx = blockIdx.x * 256 + threadIdx.x;     // 0..36863, coalesced read
    int d = idx >> 7;
    int f = idx & 127;
    ccs_t[f * KD + d] = f32_to_bf16(ccs[idx]);
    if (blockIdx.x == 0 && threadIdx.x < 128) {
        const int fc = threadIdx.x;
        float s = 0.f;
        #pragma unroll 8
        for (int dd = 0; dd < KD; ++dd) {
            float v = ccs[dd * NF + fc];
            s += v * v;
        }
        c_sq[fc] = s;
    }
}

// --- Main: one block per (8-row stripe, b). 4 strips x 2 rows, rolling 6-row ring.
__global__ __launch_bounds__(256) void rbf_main(const float* __restrict__ x,
                                                const unsigned short* __restrict__ ccs_t,
                                                const float* __restrict__ c_sq,
                                                const float* __restrict__ beta,
                                                float* __restrict__ out) {
    __shared__ unsigned short xs[SLOTS * RPX * XP];   // 43776 B
    __shared__ float colsum[SLOTS * CSP];             // 2784 B
    __shared__ float p_sq[2 * 112];                   // 896 B -> 47.4 KB total

    const int t = threadIdx.x;
    const int y0 = blockIdx.x * 8;      // 0,8,...,104
    const int b  = blockIdx.y;          // 0..31
    const int ns = (HO - y0 >= 8) ? 4 : ((HO - y0) >> 1);   // 4, or 3 for y0=104
    // NOTE: max staged row = y0 + 2*(ns-2) + 5 -> 105 (ns=4) or 111 (ns=3): never OOB, no clamp.

    const int lane  = t & 63;
    const int wave  = t >> 6;            // 4 waves x 32 filters
    const int laneM = lane & 15;
    const int quad  = lane >> 4;
    const int pl    = laneM & 1;         // pair parity for full-line stores

    // --- Prologue stage: rows m=0..3 -> slots 0..3. 3584 float4 units = 14*256 exact.
    #pragma unroll
    for (int p = 0; p < 14; ++p) {
        int idx = t + p * 256;
        int q = idx & 7;              // channel quarter (4 floats); == t&7 (lane-aligned)
        int ic = idx >> 3;            // 0..447 = i*112 + col
        int col = ic % 112;
        int i = ic / 112;             // 0..3
        const float4 v = *(const float4*)(x + ((size_t)(b * HH + y0 + i) * WW + col) * CC + q * 4);
        unsigned short h0 = f32_to_bf16(v.x), h1 = f32_to_bf16(v.y);
        unsigned short h2 = f32_to_bf16(v.z), h3 = f32_to_bf16(v.w);
        uint2 pk;
        pk.x = (unsigned)h0 | ((unsigned)h1 << 16);
        pk.y = (unsigned)h2 | ((unsigned)h3 << 16);
        *(uint2*)(&xs[(i * RPX + col) * XP + q * 4]) = pk;
        float part = v.x * v.x + v.y * v.y + v.z * v.z + v.w * v.w;
        part += __shfl_xor(part, 1);
        part += __shfl_xor(part, 2);
        part += __shfl_xor(part, 4);
        if (q == 0) colsum[i * CSP + col] = part;
    }
    __syncthreads();

    // p_sq for strip 0 (rows m=0,1; slots r+i directly)
    if (t < 224) {
        int r = t / 112, c = t - (t / 112) * 112;
        float s = 0.f;
        #pragma unroll
        for (int i = 0; i < 3; ++i)
            #pragma unroll
            for (int j = 0; j < 3; ++j)
                s += colsum[(r + i) * CSP + c + j];   // c>=110 reads in-pitch garbage -> masked px only
        p_sq[t] = s;
    }
    __syncthreads();

    const unsigned short* ap0 = ccs_t + (size_t)(wave * 32 + laneM) * KD + quad * 8;
    const unsigned short* ap1 = ap0 + 16 * KD;

    const int fb = wave * 32 + quad * 4;
    const float4 cs0 = *(const float4*)(c_sq + fb);
    const float4 cs1 = *(const float4*)(c_sq + fb + 16);
    const float4 bt0 = *(const float4*)(beta + fb);
    const float4 bt1 = *(const float4*)(beta + fb + 16);

    float4 pre[7];   // 2-row prefetch (28 VGPR held across the MFMA phase)

    for (int k = 0; k < ns; ++k) {
        const bool more = (k < ns - 1);

        // 1) Issue next-2-rows global loads NOW; consumed after barrier B.
        if (more) {
            #pragma unroll
            for (int p = 0; p < 7; ++p) {
                int idx = t + p * 256;
                int ic = idx >> 3;            // 0..223 = i*112 + col
                int q = idx & 7;
                int col = ic % 112;
                int i = ic / 112;             // 0,1
                pre[p] = *(const float4*)(x + ((size_t)(b * HH + y0 + 2 * k + 4 + i) * WW + col) * CC + q * 4);
            }
        }

        // slot pixel-bases for rows m = 2k..2k+3
        int sb[4];
        #pragma unroll
        for (int d = 0; d < 4; ++d) sb[d] = ((2 * k + d) % SLOTS) * RPX;

        // 2) MFMA + epilogue for rows m=2k, 2k+1
        for (int r = 0; r < 2; ++r) {
            f32x4 acc[7][2];
            #pragma unroll
            for (int mi = 0; mi < 7; ++mi) {
                acc[mi][0] = (f32x4){0.f, 0.f, 0.f, 0.f};
                acc[mi][1] = (f32x4){0.f, 0.f, 0.f, 0.f};
            }

            #pragma unroll
            for (int kb = 0; kb < 9; ++kb) {
                const int ki = kb / 3, kj = kb % 3;
                bf16x8 a0 = *(const bf16x8*)(ap0 + kb * 32);
                bf16x8 a1 = *(const bf16x8*)(ap1 + kb * 32);
                #pragma unroll
                for (int mi = 0; mi < 7; ++mi) {
                    const bf16x8 bf = *(const bf16x8*)(&xs[(sb[r + ki] + mi * 16 + laneM + kj) * XP + quad * 8]);
                    acc[mi][0] = __builtin_amdgcn_mfma_f32_16x16x32_bf16(a0, bf, acc[mi][0], 0, 0, 0);
                    acc[mi][1] = __builtin_amdgcn_mfma_f32_16x16x32_bf16(a1, bf, acc[mi][1], 0, 0, 0);
                }
            }

            // Epilogue: full-line nt stores via lane-pair swap (R9 win).
            float* orow = out + (size_t)((b * HO + y0 + 2 * k + r) * WO) * NF;
            #pragma unroll
            for (int mi = 0; mi < 7; ++mi) {
                const int px = mi * 16 + laneM;
                const float ps = p_sq[r * 112 + px];
                f32x4 o0, o1;
                o0[0] = __expf(-bt0.x * (ps - 2.f * acc[mi][0][0] + cs0.x));
                o0[1] = __expf(-bt0.y * (ps - 2.f * acc[mi][0][1] + cs0.y));
                o0[2] = __expf(-bt0.z * (ps - 2.f * acc[mi][0][2] + cs0.z));
                o0[3] = __expf(-bt0.w * (ps - 2.f * acc[mi][0][3] + cs0.w));
                o1[0] = __expf(-bt1.x * (ps - 2.f * acc[mi][1][0] + cs1.x));
                o1[1] = __expf(-bt1.y * (ps - 2.f * acc[mi][1][1] + cs1.y));
                o1[2] = __expf(-bt1.z * (ps - 2.f * acc[mi][1][2] + cs1.z));
                o1[3] = __expf(-bt1.w * (ps - 2.f * acc[mi][1][3] + cs1.w));

                f32x4 sendv = pl ? o0 : o1;
                f32x4 recv;
                recv[0] = __shfl_xor(sendv[0], 1);
                recv[1] = __shfl_xor(sendv[1], 1);
                recv[2] = __shfl_xor(sendv[2], 1);
                recv[3] = __shfl_xor(sendv[3], 1);
                const f32x4 v1 = pl ? recv : o0;   // even-pixel full line
                const f32x4 v2 = pl ? o1 : recv;   // odd-pixel full line

                const int pxe = mi * 16 + (laneM & ~1);
                float* op1 = orow + (size_t)pxe * NF + fb + pl * 16;
                if (pxe < WO)
                    __builtin_nontemporal_store(v1, (f32x4*)op1);
                if (pxe + 1 < WO)
                    __builtin_nontemporal_store(v2, (f32x4*)(op1 + NF));
            }
        }

        if (more) {
            __syncthreads();   // B: all waves done reading old ring slots

            // 3) Drain prefetch -> cvt -> ring slots (2k+4)%6, (2k+5)%6 + colsum
            #pragma unroll
            for (int p = 0; p < 7; ++p) {
                int idx = t + p * 256;
                int q = idx & 7;
                int ic = idx >> 3;
                int col = ic % 112;
                int i = ic / 112;
                int sl = (2 * k + 4 + i) % SLOTS;
                const float4 v = pre[p];
                unsigned short h0 = f32_to_bf16(v.x), h1 = f32_to_bf16(v.y);
                unsigned short h2 = f32_to_bf16(v.z), h3 = f32_to_bf16(v.w);
                uint2 pk;
                pk.x = (unsigned)h0 | ((unsigned)h1 << 16);
                pk.y = (unsigned)h2 | ((unsigned)h3 << 16);
                *(uint2*)(&xs[(sl * RPX + col) * XP + q * 4]) = pk;
                float part = v.x * v.x + v.y * v.y + v.z * v.z + v.w * v.w;
                part += __shfl_xor(part, 1);
                part += __shfl_xor(part, 2);
                part += __shfl_xor(part, 4);
                if (q == 0) colsum[sl * CSP + col] = part;
            }
            __syncthreads();   // C: colsum visible

            // 4) p_sq for strip k+1 (rows m=2k+2, 2k+3)
            if (t < 224) {
                int r = t / 112, c = t - (t / 112) * 112;
                float s = 0.f;
                #pragma unroll
                for (int i = 0; i < 3; ++i) {
                    int sl = (2 * k + 2 + r + i) % SLOTS;
                    #pragma unroll
                    for (int j = 0; j < 3; ++j)
                        s += colsum[sl * CSP + c + j];
                }
                p_sq[t] = s;
            }
            __syncthreads();   // A: p_sq visible
        }
    }
}

extern "C" void kernel_launch(void* const* d_in, const int* in_sizes, int n_in,
                              void* d_out, int out_size, void* d_ws, size_t ws_size,
                              hipStream_t stream) {
    const float* x    = (const float*)d_in[0];
    const float* ccs  = (const float*)d_in[1];
    const float* beta = (const float*)d_in[2];
    float* out = (float*)d_out;

    unsigned short* ccs_t = (unsigned short*)d_ws;                              // 128*288 bf16
    float* c_sq = (float*)((char*)d_ws + 128 * KD * sizeof(unsigned short));    // 128 f32

    rbf_prologue<<<144, 256, 0, stream>>>(ccs, ccs_t, c_sq);
    rbf_main<<<dim3(14, 32), 256, 0, stream>>>(x, ccs_t, c_sq, beta, out);
}

// Round 8
// 275.919 us; speedup vs baseline: 1.0599x; 1.0599x over previous
//
#include <hip/hip_runtime.h>

// RBFolution: out[b,y,x,f] = exp(-beta[f] * (||patch||^2 - 2 patch.ccs[:,f] + ||ccs[:,f]||^2))
// x: [32,112,112,32] f32, ccs: [288,128] f32, beta: [128] f32, out: [32,110,110,128] f32
//
// bf16 MFMA implicit GEMM; p_sq/c_sq fp32-exact (only cross term bf16, err ~1e-5).
// R12: ORPB=1, 3520 blocks. Empirical ledger: block-count is the ONE responsive lever
// (1760->113us, 896->118, 448->137); R11 counters proved refetch is L3-absorbed
// (FETCH 31.5MB < 51MB input) and write-amp is fixed (WRITE 193.6MB == output).
// So: minimize per-block granularity. Stage 3 rows, compute 1 row. LDS 23.7KB ->
// more co-resident blocks; VGPR ~64 (no prefetch regs, no caps -- R5 lesson).
// Logical fetch 3x (154MB) is L3-served; staging VALU +50%/row vs R9 (VALU was 13%).

typedef __attribute__((ext_vector_type(8))) short bf16x8;
typedef __attribute__((ext_vector_type(4))) float f32x4;

#define HH 112
#define WW 112
#define CC 32
#define HO 110
#define WO 110
#define NF 128
#define KD 288
#define RPX 114        // pixels per staged row (reads reach px 113)
#define XP 32          // bf16 elems per pixel (64 B)
#define CSP 116        // colsum row pitch

__device__ __forceinline__ unsigned short f32_to_bf16(float f) {
    unsigned u = __float_as_uint(f);
    unsigned r = u + 0x7FFFu + ((u >> 16) & 1u);   // round-to-nearest-even
    return (unsigned short)(r >> 16);
}

// --- Prologue: ccs [288][128] f32 -> ccs_t [128][288] bf16 (all blocks);
//     block 0 threads 0..127 also compute c_sq[f] = sum_d ccs[d][f]^2.
__global__ __launch_bounds__(256) void rbf_prologue(const float* __restrict__ ccs,
                                                    unsigned short* __restrict__ ccs_t,
                                                    float* __restrict__ c_sq) {
    int idx = blockIdx.x * 256 + threadIdx.x;     // 0..36863, coalesced read
    int d = idx >> 7;
    int f = idx & 127;
    ccs_t[f * KD + d] = f32_to_bf16(ccs[idx]);
    if (blockIdx.x == 0 && threadIdx.x < 128) {
        const int fc = threadIdx.x;
        float s = 0.f;
        #pragma unroll 8
        for (int dd = 0; dd < KD; ++dd) {
            float v = ccs[dd * NF + fc];
            s += v * v;
        }
        c_sq[fc] = s;
    }
}

// --- Main: one block per (output row, b). Stage 3 input rows, compute 1 output row.
__global__ __launch_bounds__(256) void rbf_main(const float* __restrict__ x,
                                                const unsigned short* __restrict__ ccs_t,
                                                const float* __restrict__ c_sq,
                                                const float* __restrict__ beta,
                                                float* __restrict__ out) {
    __shared__ unsigned short xs[3 * RPX * XP];   // 21888 B
    __shared__ float colsum[3 * CSP];             // 1392 B
    __shared__ float p_sq[112];                   // 448 B -> 23.7 KB total

    const int t = threadIdx.x;
    const int y0 = blockIdx.x;      // 0..109 (output row; stages input rows y0..y0+2, max 111)
    const int b  = blockIdx.y;      // 0..31

    const int lane  = t & 63;
    const int wave  = t >> 6;            // 4 waves x 32 filters
    const int laneM = lane & 15;
    const int quad  = lane >> 4;
    const int pl    = laneM & 1;         // pair parity for full-line stores

    // Stage x[y0..y0+2][0..111][0..31] -> LDS bf16; colsum from fp32 (exact p_sq).
    // 2688 float4 units = 10.5 * 256 (last iteration: waves 2,3 idle -- wave-uniform).
    #pragma unroll
    for (int p = 0; p < 11; ++p) {
        int idx = t + p * 256;
        if (idx < 3 * 112 * 8) {
            int q = idx & 7;              // channel quarter (4 floats)
            int ic = idx >> 3;            // 0..335 = i*112 + col
            int col = ic % 112;
            int i = ic / 112;             // 0..2
            const float4 v = *(const float4*)(x + ((size_t)(b * HH + y0 + i) * WW + col) * CC + q * 4);
            unsigned short h0 = f32_to_bf16(v.x), h1 = f32_to_bf16(v.y);
            unsigned short h2 = f32_to_bf16(v.z), h3 = f32_to_bf16(v.w);
            uint2 pk;
            pk.x = (unsigned)h0 | ((unsigned)h1 << 16);
            pk.y = (unsigned)h2 | ((unsigned)h3 << 16);
            *(uint2*)(&xs[(i * RPX + col) * XP + q * 4]) = pk;   // 8B, contiguous per wave
            float part = v.x * v.x + v.y * v.y + v.z * v.z + v.w * v.w;
            part += __shfl_xor(part, 1);
            part += __shfl_xor(part, 2);
            part += __shfl_xor(part, 4);
            if (q == 0) colsum[i * CSP + col] = part;
        }
    }
    __syncthreads();

    if (t < 112) {
        float s = 0.f;
        #pragma unroll
        for (int i = 0; i < 3; ++i)
            #pragma unroll
            for (int j = 0; j < 3; ++j)
                s += colsum[i * CSP + t + j];   // t>=110: in-pitch garbage -> masked px only
        p_sq[t] = s;
    }
    __syncthreads();

    // A = ccs (M = filters): lane's filter-in-tile = laneM
    const unsigned short* ap0 = ccs_t + (size_t)(wave * 32 + laneM) * KD + quad * 8;
    const unsigned short* ap1 = ap0 + 16 * KD;

    // per-lane 4 consecutive filters (rows of D): f = wave*32 + ft*16 + quad*4 + e
    const int fb = wave * 32 + quad * 4;
    const float4 cs0 = *(const float4*)(c_sq + fb);
    const float4 cs1 = *(const float4*)(c_sq + fb + 16);
    const float4 bt0 = *(const float4*)(beta + fb);
    const float4 bt1 = *(const float4*)(beta + fb + 16);

    f32x4 acc[7][2];
    #pragma unroll
    for (int mi = 0; mi < 7; ++mi) {
        acc[mi][0] = (f32x4){0.f, 0.f, 0.f, 0.f};
        acc[mi][1] = (f32x4){0.f, 0.f, 0.f, 0.f};
    }

    #pragma unroll
    for (int kb = 0; kb < 9; ++kb) {     // one k-block per tap (ki,kj), K=32 channels
        const int ki = kb / 3, kj = kb % 3;
        bf16x8 a0 = *(const bf16x8*)(ap0 + kb * 32);
        bf16x8 a1 = *(const bf16x8*)(ap1 + kb * 32);
        #pragma unroll
        for (int mi = 0; mi < 7; ++mi) {
            // B[k = quad*8+j][n = laneM]: pixel px = mi*16+laneM+kj, staged row ki
            const bf16x8 bf = *(const bf16x8*)(&xs[(ki * RPX + mi * 16 + laneM + kj) * XP + quad * 8]);
            acc[mi][0] = __builtin_amdgcn_mfma_f32_16x16x32_bf16(a0, bf, acc[mi][0], 0, 0, 0);
            acc[mi][1] = __builtin_amdgcn_mfma_f32_16x16x32_bf16(a1, bf, acc[mi][1], 0, 0, 0);
        }
    }

    // Epilogue: lane holds pixel px = mi*16+laneM, filters {fb..fb+3, fb+16..fb+19}.
    // Lane-pair swap (xor 1): instr 1 writes EVEN pixels' full 128B lines, instr 2 ODD.
    float* orow = out + (size_t)((b * HO + y0) * WO) * NF;
    #pragma unroll
    for (int mi = 0; mi < 7; ++mi) {
        const int px = mi * 16 + laneM;
        const float ps = p_sq[px];
        f32x4 o0, o1;
        o0[0] = __expf(-bt0.x * (ps - 2.f * acc[mi][0][0] + cs0.x));
        o0[1] = __expf(-bt0.y * (ps - 2.f * acc[mi][0][1] + cs0.y));
        o0[2] = __expf(-bt0.z * (ps - 2.f * acc[mi][0][2] + cs0.z));
        o0[3] = __expf(-bt0.w * (ps - 2.f * acc[mi][0][3] + cs0.w));
        o1[0] = __expf(-bt1.x * (ps - 2.f * acc[mi][1][0] + cs1.x));
        o1[1] = __expf(-bt1.y * (ps - 2.f * acc[mi][1][1] + cs1.y));
        o1[2] = __expf(-bt1.z * (ps - 2.f * acc[mi][1][2] + cs1.z));
        o1[3] = __expf(-bt1.w * (ps - 2.f * acc[mi][1][3] + cs1.w));

        // even lane sends its ft1 half, odd lane sends its ft0 half; partner receives.
        f32x4 sendv = pl ? o0 : o1;
        f32x4 recv;
        recv[0] = __shfl_xor(sendv[0], 1);
        recv[1] = __shfl_xor(sendv[1], 1);
        recv[2] = __shfl_xor(sendv[2], 1);
        recv[3] = __shfl_xor(sendv[3], 1);
        const f32x4 v1 = pl ? recv : o0;   // even-pixel full line
        const f32x4 v2 = pl ? o1 : recv;   // odd-pixel full line

        const int pxe = mi * 16 + (laneM & ~1);   // even pixel of the pair
        float* op1 = orow + (size_t)pxe * NF + fb + pl * 16;
        if (pxe < WO)
            __builtin_nontemporal_store(v1, (f32x4*)op1);
        if (pxe + 1 < WO)
            __builtin_nontemporal_store(v2, (f32x4*)(op1 + NF));
    }
}

extern "C" void kernel_launch(void* const* d_in, const int* in_sizes, int n_in,
                              void* d_out, int out_size, void* d_ws, size_t ws_size,
                              hipStream_t stream) {
    const float* x    = (const float*)d_in[0];
    const float* ccs  = (const float*)d_in[1];
    const float* beta = (const float*)d_in[2];
    float* out = (float*)d_out;

    unsigned short* ccs_t = (unsigned short*)d_ws;                              // 128*288 bf16
    float* c_sq = (float*)((char*)d_ws + 128 * KD * sizeof(unsigned short));    // 128 f32

    rbf_prologue<<<144, 256, 0, stream>>>(ccs, ccs_t, c_sq);
    rbf_main<<<dim3(110, 32), 256, 0, stream>>>(x, ccs_t, c_sq, beta, out);
}